// Round 21
// baseline (113.114 us; speedup 1.0000x reference)
//
#include <hip/hip_runtime.h>
#include <hip/hip_bf16.h>

// B=2, S=2048, H=16, D=64, D_MODEL=1024, M=B*S=4096
// ws layout (bytes):
//   WT  @ 0MB  : [4][1024][1024] bf16 (w_q^T, w_k^T, w_v^T, w_o^T)  8MB
//   Qh  @ 32MB : [32][2048][64]  bf16 (scaled by 0.125*log2e)       8MB
//   Kh  @ 40MB : [32][2048][64]  bf16                               8MB
//   Vt  @ 48MB : [32][64][2048]  bf16 (per-head transposed V)       8MB
//   Ob  @ 56MB : [4096][1024]    bf16 (attention output)            8MB

using bf16x8 = __attribute__((ext_vector_type(8))) short;
using f32x4  = __attribute__((ext_vector_type(4))) float;
using u32x4  = __attribute__((ext_vector_type(4))) unsigned;
typedef unsigned short u16;
using u16x8 = __attribute__((ext_vector_type(8))) u16;

#define GLDS16(g, l) __builtin_amdgcn_global_load_lds( \
    (const __attribute__((address_space(1))) void*)(g), \
    (__attribute__((address_space(3))) void*)(l), 16, 0, 0)

#if __has_builtin(__builtin_amdgcn_exp2f)
#define EXP2(x) __builtin_amdgcn_exp2f(x)
#else
#define EXP2(x) exp2f(x)
#endif

// Raw s_barrier is IntrNoMem: pair it with compiler memory fences so LDS
// reads/writes cannot be moved across it at compile time.
__device__ __forceinline__ void block_sync() {
  __builtin_amdgcn_sched_barrier(0);
  asm volatile("" ::: "memory");
  __builtin_amdgcn_s_barrier();
  asm volatile("" ::: "memory");
  __builtin_amdgcn_sched_barrier(0);
}

__device__ __forceinline__ u16 f2bf(float f) {
  unsigned u = __builtin_bit_cast(unsigned, f);
  u += 0x7fffu + ((u >> 16) & 1u);
  return (u16)(u >> 16);
}

// packed f32->bf16 RNE (no builtin on gfx950; T12 primitive)
__device__ __forceinline__ unsigned cvt_pk_bf16(float lo, float hi) {
  unsigned r;
  asm("v_cvt_pk_bf16_f32 %0, %1, %2" : "=v"(r) : "v"(lo), "v"(hi));
  return r;
}

__device__ __forceinline__ float fmax3(float a, float b, float c) {
  return fmaxf(fmaxf(a, b), c);  // clang fuses to v_max3_f32
}

// ---------- kernel 1: weight transpose+convert: WT[z][n][k] = bf16(w_z[k][n]) ----------
__global__ __launch_bounds__(256) void wtrans_kernel(
    const float* __restrict__ wq, const float* __restrict__ wk,
    const float* __restrict__ wv, const float* __restrict__ wo,
    u16* __restrict__ dst) {
  __shared__ float t[32][33];
  const int z = blockIdx.z;
  const float* src = (z == 0) ? wq : (z == 1) ? wk : (z == 2) ? wv : wo;
  u16* d = dst + (size_t)z * 1024 * 1024;
  const int tx = threadIdx.x & 31, ty = threadIdx.x >> 5;
  const int bx = blockIdx.x * 32, by = blockIdx.y * 32;
#pragma unroll
  for (int j = 0; j < 4; j++)
    t[ty + j * 8][tx] = src[(size_t)(by + ty + j * 8) * 1024 + bx + tx];
  __syncthreads();
#pragma unroll
  for (int j = 0; j < 4; j++)
    d[(size_t)(bx + ty + j * 8) * 1024 + by + tx] = f2bf(t[tx][ty + j * 8]);
}

// ---------- kernel 2: fused QKV projections (128x128, 512 thr, 2-deep A) ----------
// (R19-validated: VGPR 60, no spill, WRITE 24.6MB exact.)
// In-order vmcnt queue, steady step k: entry [A[k](4),B[k](2),A[k+1](4)]=10;
//   vmcnt(6) drains A[k] -> WRITEA -> issue B[k+1](2)+A[k+2](4) (=12 out) ->
//   vmcnt(10) lgkmcnt(0) drains B[k] -> barrier -> MFMA -> barrier.
// 768 blocks; xcd=id&7 owns 4 y-panels x 8 bx per z -> A read by ONE XCD.
__global__ __launch_bounds__(512, 2) void proj_kernel(
    const float* __restrict__ qf, const float* __restrict__ kf,
    const float* __restrict__ vf, const u16* __restrict__ WT,
    u16* __restrict__ Qh, u16* __restrict__ Kh, u16* __restrict__ Vt) {
  __shared__ u16 lds[24576];   // [0,8192): A; [8192,16384): B0; [16384,24576): B1
  const int id = blockIdx.x;
  const int xcd = id & 7, l = id >> 3;      // l in [0,96)
  const int z = l >> 5, rem = l & 31;       // 32 blocks per XCD per z
  const int by = xcd * 4 + (rem >> 3);      // 4 y-panels per XCD
  const int bx = rem & 7;
  const int arow0 = by * 128, bcol0 = bx * 128;
  const float* A = (z == 0) ? qf : (z == 1) ? kf : vf;
  const u16* Bw = WT + (size_t)z * 1024 * 1024;

  const int tid = threadIdx.x;
  const int lane = tid & 63, wave = tid >> 6;
  const int lr = lane & 15, lg = lane >> 4;
  const int wr = (wave >> 2) * 64;   // M offset (0/64), 2 M-groups
  const int wc = (wave & 3) * 32;    // N offset (0/32/64/96), 4 N-groups
  const int ar = tid >> 2, ac0 = (tid & 3) * 16;  // A stage: row (0..127), col
  f32x4 acc[4][2] = {};
  f32x4 fa0[4], fa1[4];   // 2-deep in-flight A (16 VGPRs each)

  auto LOADA0 = [&](int kt) {
    const float* ap = A + (size_t)(arow0 + ar) * 1024 + kt + ac0;
#pragma unroll
    for (int j = 0; j < 4; j++) fa0[j] = *(const f32x4*)(ap + 4 * j);
  };
  auto LOADA1 = [&](int kt) {
    const float* ap = A + (size_t)(arow0 + ar) * 1024 + kt + ac0;
#pragma unroll
    for (int j = 0; j < 4; j++) fa1[j] = *(const f32x4*)(ap + 4 * j);
  };
  auto GLDSB = [&](int kt, int nb) {
    u16* bd = lds + 8192 + nb * 8192;
#pragma unroll
    for (int i = 0; i < 2; i++) {
      int o = (i * 512 + tid) * 8;
      int row = o >> 6, ch = (o >> 3) & 7;
      GLDS16(Bw + (size_t)(bcol0 + row) * 1024 + kt + ((ch ^ (row & 7)) << 3),
             bd + o);
    }
  };
  auto WRITEA0 = [&]() {
    u32x4 lo = {cvt_pk_bf16(fa0[0][0], fa0[0][1]), cvt_pk_bf16(fa0[0][2], fa0[0][3]),
                cvt_pk_bf16(fa0[1][0], fa0[1][1]), cvt_pk_bf16(fa0[1][2], fa0[1][3])};
    u32x4 hi = {cvt_pk_bf16(fa0[2][0], fa0[2][1]), cvt_pk_bf16(fa0[2][2], fa0[2][3]),
                cvt_pk_bf16(fa0[3][0], fa0[3][1]), cvt_pk_bf16(fa0[3][2], fa0[3][3])};
    const int swz = (ar & 7) << 3;
    *(u32x4*)&lds[ar * 64 + (ac0 ^ swz)] = lo;
    *(u32x4*)&lds[ar * 64 + ((ac0 + 8) ^ swz)] = hi;
  };
  auto WRITEA1 = [&]() {
    u32x4 lo = {cvt_pk_bf16(fa1[0][0], fa1[0][1]), cvt_pk_bf16(fa1[0][2], fa1[0][3]),
                cvt_pk_bf16(fa1[1][0], fa1[1][1]), cvt_pk_bf16(fa1[1][2], fa1[1][3])};
    u32x4 hi = {cvt_pk_bf16(fa1[2][0], fa1[2][1]), cvt_pk_bf16(fa1[2][2], fa1[2][3]),
                cvt_pk_bf16(fa1[3][0], fa1[3][1]), cvt_pk_bf16(fa1[3][2], fa1[3][3])};
    const int swz = (ar & 7) << 3;
    *(u32x4*)&lds[ar * 64 + (ac0 ^ swz)] = lo;
    *(u32x4*)&lds[ar * 64 + ((ac0 + 8) ^ swz)] = hi;
  };
  auto MFMAK = [&](int cb) {
    const u16* Bb = lds + 8192 + cb * 8192;
#pragma unroll
    for (int kk = 0; kk < 2; kk++) {
      bf16x8 af[4], bfr[2];
      const int ke = kk * 32 + lg * 8;
#pragma unroll
      for (int m = 0; m < 4; m++) {
        int row = wr + m * 16 + lr;
        af[m] = *(const bf16x8*)&lds[row * 64 + (ke ^ ((row & 7) << 3))];
      }
#pragma unroll
      for (int n = 0; n < 2; n++) {
        int row = wc + n * 16 + lr;
        bfr[n] = *(const bf16x8*)&Bb[row * 64 + (ke ^ ((row & 7) << 3))];
      }
#pragma unroll
      for (int m = 0; m < 4; m++)
#pragma unroll
        for (int n = 0; n < 2; n++)
          acc[m][n] = __builtin_amdgcn_mfma_f32_16x16x32_bf16(af[m], bfr[n],
                                                              acc[m][n], 0, 0, 0);
    }
  };

  // prologue: queue [A0(4), B0(2), A1(4)] = 10 outstanding
  LOADA0(0);
  GLDSB(0, 0);
  LOADA1(64);
  for (int kt = 0; kt < 896; kt += 128) {   // tiles 0..13 (7 pairs)
    asm volatile("s_waitcnt vmcnt(6)" ::: "memory");   // drain A[k]
    WRITEA0();
    GLDSB(kt + 64, 1);                                  // B[k+1]
    LOADA0(kt + 128);                                   // A[k+2]
    asm volatile("s_waitcnt vmcnt(10) lgkmcnt(0)" ::: "memory");  // drain B[k]
    block_sync();
    MFMAK(0);
    block_sync();
    asm volatile("s_waitcnt vmcnt(6)" ::: "memory");   // drain A[k+1]
    WRITEA1();
    GLDSB(kt + 128, 0);                                 // B[k+2]
    LOADA1(kt + 192);                                   // A[k+3]
    asm volatile("s_waitcnt vmcnt(10) lgkmcnt(0)" ::: "memory");  // drain B[k+1]
    block_sync();
    MFMAK(1);
    block_sync();
  }
  // tile 14 (CB=0, fa0): entry queue [A14(4), B14(2), A15(4)] = 10
  asm volatile("s_waitcnt vmcnt(6)" ::: "memory");     // drain A14
  WRITEA0();
  GLDSB(960, 1);                                        // B15
  asm volatile("s_waitcnt vmcnt(6) lgkmcnt(0)" ::: "memory");  // drain B14
  block_sync();
  MFMAK(0);
  block_sync();
  // tile 15 (CB=1, fa1): entry queue [A15(4), B15(2)] = 6
  asm volatile("s_waitcnt vmcnt(2)" ::: "memory");     // drain A15
  WRITEA1();
  asm volatile("s_waitcnt vmcnt(0) lgkmcnt(0)" ::: "memory");  // drain B15
  block_sync();
  MFMAK(1);
  block_sync();

  // epilogues: LDS transpose (T = lds[0..16384), 32KB) -> u16x8 stores
  if (z == 2) {
    // V: T[c][s] (128x128, swizzled) -> Vt[(b*16+h)*64+d][s]
    u16* T = lds;
#pragma unroll
    for (int m = 0; m < 4; m++)
#pragma unroll
      for (int n = 0; n < 2; n++)
#pragma unroll
        for (int r = 0; r < 4; r++) {
          int sl = wr + m * 16 + lg * 4 + r;
          int cl = wc + n * 16 + lr;
          T[cl * 128 + (sl ^ ((cl & 7) << 3))] = f2bf(acc[m][n][r]);
        }
    __syncthreads();
    const int cl = tid >> 2, s0 = (tid & 3) * 32;
    const int gc = bcol0 + cl;
    const size_t vrow = ((size_t)(arow0 >> 11) * 16 + (gc >> 6)) * 64 + (gc & 63);
    u16* vd = Vt + vrow * 2048 + (size_t)(arow0 & 2047);
#pragma unroll
    for (int j = 0; j < 4; j++) {
      int sl = s0 + j * 8;
      *(u16x8*)&vd[sl] = *(const u16x8*)&T[cl * 128 + (sl ^ ((cl & 7) << 3))];
    }
  } else {
    // Q/K: T[s][c] (128x128, swizzled) -> dst[(bh*2048+s)*64 + c]
    const float scale = (z == 0) ? 0.18033688f : 1.0f;  // 0.125 * log2(e)
    u16* dst = (z == 0) ? Qh : Kh;
    u16* T = lds;
#pragma unroll
    for (int m = 0; m < 4; m++)
#pragma unroll
      for (int n = 0; n < 2; n++)
#pragma unroll
        for (int r = 0; r < 4; r++) {
          int sl = wr + m * 16 + lg * 4 + r;
          int cl = wc + n * 16 + lr;
          T[sl * 128 + (cl ^ ((sl & 7) << 3))] = f2bf(acc[m][n][r] * scale);
        }
    __syncthreads();
    const int h2 = tid >> 8, tt = tid & 255;
    const int rb = tt >> 3, c0 = (tt & 7) * 8;
    const size_t bh = (size_t)(arow0 >> 11) * 16 + bx * 2 + h2;
    const int cl = h2 * 64 + c0;
#pragma unroll
    for (int j = 0; j < 4; j++) {
      int row = j * 32 + rb;
      u16x8 vv = *(const u16x8*)&T[row * 128 + (cl ^ ((row & 7) << 3))];
      *(u16x8*)&dst[(bh * 2048 + (size_t)((arow0 & 2047) + row)) * 64 + c0] = vv;
    }
  }
}

// ---------- kernel 3: flash attention (paired QK^T issue, T15-lite) ----------
// 512 blocks (XCD-swizzled) x 8 waves, 128 q-rows per block, 16 per wave.
// R20's 2-tile super-step, restructured: issue BOTH QK^T MFMA clusters first
// (independent sacc0/sacc1), then softmax+PV for each. In-order issue means
// softmax(0) VALU executes while QK(1) crunches in the matrix pipe -> hides
// one QK latency per pair under the serial fmax/exp2 chain. +16 VGPR (sacc1).
// Math order unchanged (sm(1) sees mrun after sm(0)) -> bit-identical output.
__global__ __launch_bounds__(512, 4) void attn_kernel(
    const u16* __restrict__ Qh, const u16* __restrict__ Kh,
    const u16* __restrict__ Vt, u16* __restrict__ Ob) {
  __shared__ u16 kt[4][64 * 64];  // K tiles [key][d], h-swizzled rows
  __shared__ u16 vt[4][64 * 64];  // V^T tiles [d][s], xor-swizzled rows
  const int tid = threadIdx.x;
  const int lane = tid & 63, wave = tid >> 6;
  const int lr = lane & 15, lg = lane >> 4;
  const int id = blockIdx.x;
  const int swz = (id & 7) * 64 + (id >> 3);
  const int bh = swz >> 4;
  const int q0 = (swz & 15) * 128;
  const u16* Qb = Qh + ((size_t)bh * 2048 + q0) * 64;
  const u16* Kb = Kh + (size_t)bh * 2048 * 64;
  const u16* Vb = Vt + (size_t)bh * 64 * 2048;

  bf16x8 aq[2];
#pragma unroll
  for (int kk = 0; kk < 2; kk++)
    aq[kk] = *(const bf16x8*)(Qb + (wave * 16 + lr) * 64 + kk * 32 + lg * 8);

  const int hsw = (lr & 3) | (((lr >> 2) & 1) << 2);
  int koff[2][4];
#pragma unroll
  for (int n = 0; n < 4; n++) {
    int kr = 32 * (n >> 1) + 8 * (lr >> 2) + 4 * (n & 1) + (lr & 3);
#pragma unroll
    for (int kk = 0; kk < 2; kk++)
      koff[kk][n] = kr * 64 + ((kk * 32 + lg * 8) ^ (hsw << 3));
  }
  int voff[2][4];
#pragma unroll
  for (int n = 0; n < 4; n++) {
    int d = n * 16 + lr;
#pragma unroll
    for (int ks = 0; ks < 2; ks++)
      voff[ks][n] = d * 64 + ((ks * 32 + lg * 8) ^ ((d & 7) << 3));
  }

  const int o0 = tid * 8;
  const int srow = tid >> 3, sch = tid & 7;
  const int hk = (srow & 3) | (((srow >> 3) & 1) << 2);
  const u16* kg = Kb + (size_t)srow * 64 + ((sch ^ hk) << 3);
  const u16* vg = Vb + (size_t)srow * 2048 + ((sch ^ (srow & 7)) << 3);

  f32x4 oacc[4] = {};
  float mrun = -1e30f, lrun = 0.f;

  auto STAGE = [&](int t, int b) {
    GLDS16(kg + (size_t)t * 4096, &kt[0][0] + b * 4096 + o0);
    GLDS16(vg + t * 64, &vt[0][0] + b * 4096 + o0);
  };

  auto QKT = [&](int cur, f32x4 (&sacc)[4]) {
    __builtin_amdgcn_s_setprio(1);
#pragma unroll
    for (int kk = 0; kk < 2; kk++) {
#pragma unroll
      for (int n = 0; n < 4; n++) {
        bf16x8 ka = *(const bf16x8*)&kt[cur][koff[kk][n]];
        sacc[n] = __builtin_amdgcn_mfma_f32_16x16x32_bf16(ka, aq[kk],
                                                          sacc[n], 0, 0, 0);
      }
    }
    __builtin_amdgcn_s_setprio(0);
  };

  auto SMPV = [&](int cur, f32x4 (&sacc)[4]) {
    float t0 = fmax3(sacc[0][0], sacc[0][1], sacc[0][2]);
    float t1 = fmax3(sacc[0][3], sacc[1][0], sacc[1][1]);
    float t2 = fmax3(sacc[1][2], sacc[1][3], sacc[2][0]);
    float t3 = fmax3(sacc[2][1], sacc[2][2], sacc[2][3]);
    float t4 = fmax3(sacc[3][0], sacc[3][1], sacc[3][2]);
    float mx = fmaxf(fmax3(t0, t1, t2), fmax3(t3, t4, sacc[3][3]));
    mx = fmaxf(mx, __shfl_xor(mx, 16));
    mx = fmaxf(mx, __shfl_xor(mx, 32));
    float mnew = fmaxf(mrun, mx);
    if (__all(mx - mrun <= 8.0f)) {
      mnew = mrun;
    } else {
      float corr = EXP2(mrun - mnew);
      mrun = mnew;
      lrun *= corr;
      float cr[4];
#pragma unroll
      for (int r = 0; r < 4; r++) cr[r] = __shfl(corr, lg * 4 + r);
#pragma unroll
      for (int n = 0; n < 4; n++)
#pragma unroll
        for (int r = 0; r < 4; r++) oacc[n][r] *= cr[r];
    }
    float psum = 0.f;
#pragma unroll
    for (int n = 0; n < 4; n++)
#pragma unroll
      for (int r = 0; r < 4; r++) {
        float p = EXP2(sacc[n][r] - mnew);
        sacc[n][r] = p;
        psum += p;
      }
    psum += __shfl_xor(psum, 16);
    psum += __shfl_xor(psum, 32);
    lrun += psum;
    u32x4 w0 = {cvt_pk_bf16(sacc[0][0], sacc[0][1]),
                cvt_pk_bf16(sacc[0][2], sacc[0][3]),
                cvt_pk_bf16(sacc[1][0], sacc[1][1]),
                cvt_pk_bf16(sacc[1][2], sacc[1][3])};
    u32x4 w1 = {cvt_pk_bf16(sacc[2][0], sacc[2][1]),
                cvt_pk_bf16(sacc[2][2], sacc[2][3]),
                cvt_pk_bf16(sacc[3][0], sacc[3][1]),
                cvt_pk_bf16(sacc[3][2], sacc[3][3])};
    bf16x8 pa0 = __builtin_bit_cast(bf16x8, w0);
    bf16x8 pa1 = __builtin_bit_cast(bf16x8, w1);
    __builtin_amdgcn_s_setprio(1);
#pragma unroll
    for (int ks = 0; ks < 2; ks++) {
      bf16x8 ap = ks ? pa1 : pa0;
      bf16x8 bv[4];
#pragma unroll
      for (int n = 0; n < 4; n++)
        bv[n] = *(const bf16x8*)&vt[cur][voff[ks][n]];
#pragma unroll
      for (int n = 0; n < 4; n++)
        oacc[n] = __builtin_amdgcn_mfma_f32_16x16x32_bf16(ap, bv[n],
                                                          oacc[n], 0, 0, 0);
    }
    __builtin_amdgcn_s_setprio(0);
  };

  auto COMPUTE2 = [&](int c0, int c1) {  // c0,c1 literals at call sites
    f32x4 s0[4] = {}, s1[4] = {};
    QKT(c0, s0);
    QKT(c1, s1);   // issued before sm(0): matrix pipe stays fed during VALU
    SMPV(c0, s0);
    SMPV(c1, s1);
  };

#define VMC4 asm volatile("s_waitcnt vmcnt(4)" ::: "memory")
#define VMC0 asm volatile("s_waitcnt vmcnt(0)" ::: "memory")
  STAGE(0, 0); STAGE(1, 1);
  // 16 super-steps, 2 tiles each; unrolled x2 so all buf indices are literals
  for (int t = 0; t < 28; t += 4) {   // steps for tiles 0..27
    STAGE(t + 2, 2); STAGE(t + 3, 3); VMC4; block_sync();
    COMPUTE2(0, 1); block_sync();
    STAGE(t + 4, 0); STAGE(t + 5, 1); VMC4; block_sync();
    COMPUTE2(2, 3); block_sync();
  }
  // tiles 28,29 in bufs 0,1 (staged by last iter); stage 30,31
  STAGE(30, 2); STAGE(31, 3); VMC4; block_sync();
  COMPUTE2(0, 1); block_sync();
  VMC0; block_sync();
  COMPUTE2(2, 3);
#undef VMC4
#undef VMC0

  const int b = bh >> 4, h = bh & 15;
  float inv = 1.0f / lrun;
  float ivr[4];
#pragma unroll
  for (int r = 0; r < 4; r++) ivr[r] = __shfl(inv, lg * 4 + r);
#pragma unroll
  for (int r = 0; r < 4; r++) {
    int qrow = q0 + wave * 16 + lg * 4 + r;
#pragma unroll
    for (int n = 0; n < 4; n++) {
      int d = n * 16 + lr;
      Ob[((size_t)b * 2048 + qrow) * 1024 + h * 64 + d] = f2bf(oacc[n][r] * ivr[r]);
    }
  }
}

// ---------- kernel 4: output projection (128x64 tile, XCD-chunked 512 blocks) ----------
__global__ __launch_bounds__(256) void outproj_kernel(
    const u16* __restrict__ Ob, const u16* __restrict__ WoT,
    float* __restrict__ out) {
  __shared__ u16 ldsA[128 * 64];  // 16KB, swizzled rows
  __shared__ u16 ldsB[64 * 64];   //  8KB, swizzled rows
  const int tid = threadIdx.x;
  const int lane = tid & 63, wave = tid >> 6;
  const int lr = lane & 15, lg = lane >> 4;
  const int wr = (wave >> 1) * 64;  // M offset (0/64)
  const int wc = (wave & 1) * 32;   // N offset (0/32)
  const int id = blockIdx.x;
  const int xcd = id & 7, l = id >> 3;   // l in [0,64)
  const int by = xcd * 4 + (l >> 4);     // 0..31
  const int bx = l & 15;                 // 0..15
  const int arow0 = by * 128, bcol0 = bx * 64;
  f32x4 acc[4][2] = {};
  for (int kt = 0; kt < 1024; kt += 64) {
#pragma unroll
    for (int i = 0; i < 4; i++) {
      int o = (i * 256 + tid) * 8;
      int row = o >> 6, ch = (o >> 3) & 7;
      int sc = (ch ^ (row & 7)) << 3;
      GLDS16(Ob + (size_t)(arow0 + row) * 1024 + kt + sc, &ldsA[o]);
    }
#pragma unroll
    for (int i = 0; i < 2; i++) {
      int o = (i * 256 + tid) * 8;
      int row = o >> 6, ch = (o >> 3) & 7;
      int sc = (ch ^ (row & 7)) << 3;
      GLDS16(WoT + (size_t)(bcol0 + row) * 1024 + kt + sc, &ldsB[o]);
    }
    __syncthreads();
#pragma unroll
    for (int kk = 0; kk < 2; kk++) {
      const int ke = kk * 32 + lg * 8;
      bf16x8 af[4], bfr[2];
#pragma unroll
      for (int m = 0; m < 4; m++) {
        int row = wr + m * 16 + lr;
        af[m] = *(const bf16x8*)&ldsA[row * 64 + (ke ^ ((row & 7) << 3))];
      }
#pragma unroll
      for (int n = 0; n < 2; n++) {
        int row = wc + n * 16 + lr;
        bfr[n] = *(const bf16x8*)&ldsB[row * 64 + (ke ^ ((row & 7) << 3))];
      }
#pragma unroll
      for (int m = 0; m < 4; m++)
#pragma unroll
        for (int n = 0; n < 2; n++)
          acc[m][n] = __builtin_amdgcn_mfma_f32_16x16x32_bf16(af[m], bfr[n],
                                                              acc[m][n], 0, 0, 0);
    }
    __syncthreads();
  }
#pragma unroll
  for (int m = 0; m < 4; m++)
#pragma unroll
    for (int n = 0; n < 2; n++)
#pragma unroll
      for (int r = 0; r < 4; r++) {
        int gr = arow0 + wr + m * 16 + lg * 4 + r;
        int gc = bcol0 + wc + n * 16 + lr;
        out[(size_t)gr * 1024 + gc] = acc[m][n][r];
      }
}

extern "C" void kernel_launch(void* const* d_in, const int* in_sizes, int n_in,
                              void* d_out, int out_size, void* d_ws, size_t ws_size,
                              hipStream_t stream) {
  const float* q  = (const float*)d_in[0];
  const float* k  = (const float*)d_in[1];
  const float* v  = (const float*)d_in[2];
  const float* wq = (const float*)d_in[3];
  const float* wk = (const float*)d_in[4];
  const float* wv = (const float*)d_in[5];
  const float* wo = (const float*)d_in[6];
  float* out = (float*)d_out;
  char* ws = (char*)d_ws;

  u16* WT = (u16*)ws;                                    // [4][1024][1024]
  u16* Qh = (u16*)(ws + (size_t)32 * 1024 * 1024);       // [32][2048][64]
  u16* Kh = (u16*)(ws + (size_t)40 * 1024 * 1024);       // [32][2048][64]
  u16* Vt = (u16*)(ws + (size_t)48 * 1024 * 1024);       // [32][64][2048]
  u16* Ob = (u16*)(ws + (size_t)56 * 1024 * 1024);       // [4096][1024]

  wtrans_kernel<<<dim3(32, 32, 4), 256, 0, stream>>>(wq, wk, wv, wo, WT);
  proj_kernel<<<dim3(768), 512, 0, stream>>>(q, k, v, WT, Qh, Kh, Vt);
  attn_kernel<<<dim3(512), 512, 0, stream>>>(Qh, Kh, Vt, Ob);
  outproj_kernel<<<dim3(512), 256, 0, stream>>>(Ob, WT + (size_t)3 * 1024 * 1024, out);
}

// Round 22
// 112.877 us; speedup vs baseline: 1.0021x; 1.0021x over previous
//
#include <hip/hip_runtime.h>
#include <hip/hip_bf16.h>

// B=2, S=2048, H=16, D=64, D_MODEL=1024, M=B*S=4096
// ws layout (bytes):
//   WT  @ 0MB  : [4][1024][1024] bf16 (w_q^T, w_k^T, w_v^T, w_o^T)  8MB
//   Qh  @ 32MB : [32][2048][64]  bf16 (scaled by 0.125*log2e)       8MB
//   Kh  @ 40MB : [32][2048][64]  bf16                               8MB
//   Vt  @ 48MB : [32][64][2048]  bf16 (per-head transposed V)       8MB
//   Ob  @ 56MB : [4096][1024]    bf16 (attention output)            8MB

using bf16x8 = __attribute__((ext_vector_type(8))) short;
using f32x4  = __attribute__((ext_vector_type(4))) float;
using u32x4  = __attribute__((ext_vector_type(4))) unsigned;
typedef unsigned short u16;
using u16x8 = __attribute__((ext_vector_type(8))) u16;

#define GLDS16(g, l) __builtin_amdgcn_global_load_lds( \
    (const __attribute__((address_space(1))) void*)(g), \
    (__attribute__((address_space(3))) void*)(l), 16, 0, 0)

#if __has_builtin(__builtin_amdgcn_exp2f)
#define EXP2(x) __builtin_amdgcn_exp2f(x)
#else
#define EXP2(x) exp2f(x)
#endif

// Raw s_barrier is IntrNoMem: pair it with compiler memory fences so LDS
// reads/writes cannot be moved across it at compile time.
__device__ __forceinline__ void block_sync() {
  __builtin_amdgcn_sched_barrier(0);
  asm volatile("" ::: "memory");
  __builtin_amdgcn_s_barrier();
  asm volatile("" ::: "memory");
  __builtin_amdgcn_sched_barrier(0);
}

__device__ __forceinline__ u16 f2bf(float f) {
  unsigned u = __builtin_bit_cast(unsigned, f);
  u += 0x7fffu + ((u >> 16) & 1u);
  return (u16)(u >> 16);
}

// packed f32->bf16 RNE (no builtin on gfx950; T12 primitive)
__device__ __forceinline__ unsigned cvt_pk_bf16(float lo, float hi) {
  unsigned r;
  asm("v_cvt_pk_bf16_f32 %0, %1, %2" : "=v"(r) : "v"(lo), "v"(hi));
  return r;
}

__device__ __forceinline__ float fmax3(float a, float b, float c) {
  return fmaxf(fmaxf(a, b), c);  // clang fuses to v_max3_f32
}

// ---------- kernel 1: weight transpose+convert: WT[z][n][k] = bf16(w_z[k][n]) ----------
__global__ __launch_bounds__(256) void wtrans_kernel(
    const float* __restrict__ wq, const float* __restrict__ wk,
    const float* __restrict__ wv, const float* __restrict__ wo,
    u16* __restrict__ dst) {
  __shared__ float t[32][33];
  const int z = blockIdx.z;
  const float* src = (z == 0) ? wq : (z == 1) ? wk : (z == 2) ? wv : wo;
  u16* d = dst + (size_t)z * 1024 * 1024;
  const int tx = threadIdx.x & 31, ty = threadIdx.x >> 5;
  const int bx = blockIdx.x * 32, by = blockIdx.y * 32;
#pragma unroll
  for (int j = 0; j < 4; j++)
    t[ty + j * 8][tx] = src[(size_t)(by + ty + j * 8) * 1024 + bx + tx];
  __syncthreads();
#pragma unroll
  for (int j = 0; j < 4; j++)
    d[(size_t)(bx + ty + j * 8) * 1024 + by + tx] = f2bf(t[tx][ty + j * 8]);
}

// ---------- kernel 2: fused QKV projections (128x128, 512 thr, 2-deep A) ----------
// (R19-validated: VGPR 60, no spill, WRITE 24.6MB exact.)
// In-order vmcnt queue, steady step k: entry [A[k](4),B[k](2),A[k+1](4)]=10;
//   vmcnt(6) drains A[k] -> WRITEA -> issue B[k+1](2)+A[k+2](4) (=12 out) ->
//   vmcnt(10) lgkmcnt(0) drains B[k] -> barrier -> MFMA -> barrier.
// 768 blocks; xcd=id&7 owns 4 y-panels x 8 bx per z -> A read by ONE XCD.
__global__ __launch_bounds__(512, 2) void proj_kernel(
    const float* __restrict__ qf, const float* __restrict__ kf,
    const float* __restrict__ vf, const u16* __restrict__ WT,
    u16* __restrict__ Qh, u16* __restrict__ Kh, u16* __restrict__ Vt) {
  __shared__ u16 lds[24576];   // [0,8192): A; [8192,16384): B0; [16384,24576): B1
  const int id = blockIdx.x;
  const int xcd = id & 7, l = id >> 3;      // l in [0,96)
  const int z = l >> 5, rem = l & 31;       // 32 blocks per XCD per z
  const int by = xcd * 4 + (rem >> 3);      // 4 y-panels per XCD
  const int bx = rem & 7;
  const int arow0 = by * 128, bcol0 = bx * 128;
  const float* A = (z == 0) ? qf : (z == 1) ? kf : vf;
  const u16* Bw = WT + (size_t)z * 1024 * 1024;

  const int tid = threadIdx.x;
  const int lane = tid & 63, wave = tid >> 6;
  const int lr = lane & 15, lg = lane >> 4;
  const int wr = (wave >> 2) * 64;   // M offset (0/64), 2 M-groups
  const int wc = (wave & 3) * 32;    // N offset (0/32/64/96), 4 N-groups
  const int ar = tid >> 2, ac0 = (tid & 3) * 16;  // A stage: row (0..127), col
  f32x4 acc[4][2] = {};
  f32x4 fa0[4], fa1[4];   // 2-deep in-flight A (16 VGPRs each)

  auto LOADA0 = [&](int kt) {
    const float* ap = A + (size_t)(arow0 + ar) * 1024 + kt + ac0;
#pragma unroll
    for (int j = 0; j < 4; j++) fa0[j] = *(const f32x4*)(ap + 4 * j);
  };
  auto LOADA1 = [&](int kt) {
    const float* ap = A + (size_t)(arow0 + ar) * 1024 + kt + ac0;
#pragma unroll
    for (int j = 0; j < 4; j++) fa1[j] = *(const f32x4*)(ap + 4 * j);
  };
  auto GLDSB = [&](int kt, int nb) {
    u16* bd = lds + 8192 + nb * 8192;
#pragma unroll
    for (int i = 0; i < 2; i++) {
      int o = (i * 512 + tid) * 8;
      int row = o >> 6, ch = (o >> 3) & 7;
      GLDS16(Bw + (size_t)(bcol0 + row) * 1024 + kt + ((ch ^ (row & 7)) << 3),
             bd + o);
    }
  };
  auto WRITEA0 = [&]() {
    u32x4 lo = {cvt_pk_bf16(fa0[0][0], fa0[0][1]), cvt_pk_bf16(fa0[0][2], fa0[0][3]),
                cvt_pk_bf16(fa0[1][0], fa0[1][1]), cvt_pk_bf16(fa0[1][2], fa0[1][3])};
    u32x4 hi = {cvt_pk_bf16(fa0[2][0], fa0[2][1]), cvt_pk_bf16(fa0[2][2], fa0[2][3]),
                cvt_pk_bf16(fa0[3][0], fa0[3][1]), cvt_pk_bf16(fa0[3][2], fa0[3][3])};
    const int swz = (ar & 7) << 3;
    *(u32x4*)&lds[ar * 64 + (ac0 ^ swz)] = lo;
    *(u32x4*)&lds[ar * 64 + ((ac0 + 8) ^ swz)] = hi;
  };
  auto WRITEA1 = [&]() {
    u32x4 lo = {cvt_pk_bf16(fa1[0][0], fa1[0][1]), cvt_pk_bf16(fa1[0][2], fa1[0][3]),
                cvt_pk_bf16(fa1[1][0], fa1[1][1]), cvt_pk_bf16(fa1[1][2], fa1[1][3])};
    u32x4 hi = {cvt_pk_bf16(fa1[2][0], fa1[2][1]), cvt_pk_bf16(fa1[2][2], fa1[2][3]),
                cvt_pk_bf16(fa1[3][0], fa1[3][1]), cvt_pk_bf16(fa1[3][2], fa1[3][3])};
    const int swz = (ar & 7) << 3;
    *(u32x4*)&lds[ar * 64 + (ac0 ^ swz)] = lo;
    *(u32x4*)&lds[ar * 64 + ((ac0 + 8) ^ swz)] = hi;
  };
  auto MFMAK = [&](int cb) {
    const u16* Bb = lds + 8192 + cb * 8192;
#pragma unroll
    for (int kk = 0; kk < 2; kk++) {
      bf16x8 af[4], bfr[2];
      const int ke = kk * 32 + lg * 8;
#pragma unroll
      for (int m = 0; m < 4; m++) {
        int row = wr + m * 16 + lr;
        af[m] = *(const bf16x8*)&lds[row * 64 + (ke ^ ((row & 7) << 3))];
      }
#pragma unroll
      for (int n = 0; n < 2; n++) {
        int row = wc + n * 16 + lr;
        bfr[n] = *(const bf16x8*)&Bb[row * 64 + (ke ^ ((row & 7) << 3))];
      }
#pragma unroll
      for (int m = 0; m < 4; m++)
#pragma unroll
        for (int n = 0; n < 2; n++)
          acc[m][n] = __builtin_amdgcn_mfma_f32_16x16x32_bf16(af[m], bfr[n],
                                                              acc[m][n], 0, 0, 0);
    }
  };

  // prologue: queue [A0(4), B0(2), A1(4)] = 10 outstanding
  LOADA0(0);
  GLDSB(0, 0);
  LOADA1(64);
  for (int kt = 0; kt < 896; kt += 128) {   // tiles 0..13 (7 pairs)
    asm volatile("s_waitcnt vmcnt(6)" ::: "memory");   // drain A[k]
    WRITEA0();
    GLDSB(kt + 64, 1);                                  // B[k+1]
    LOADA0(kt + 128);                                   // A[k+2]
    asm volatile("s_waitcnt vmcnt(10) lgkmcnt(0)" ::: "memory");  // drain B[k]
    block_sync();
    MFMAK(0);
    block_sync();
    asm volatile("s_waitcnt vmcnt(6)" ::: "memory");   // drain A[k+1]
    WRITEA1();
    GLDSB(kt + 128, 0);                                 // B[k+2]
    LOADA1(kt + 192);                                   // A[k+3]
    asm volatile("s_waitcnt vmcnt(10) lgkmcnt(0)" ::: "memory");  // drain B[k+1]
    block_sync();
    MFMAK(1);
    block_sync();
  }
  // tile 14 (CB=0, fa0): entry queue [A14(4), B14(2), A15(4)] = 10
  asm volatile("s_waitcnt vmcnt(6)" ::: "memory");     // drain A14
  WRITEA0();
  GLDSB(960, 1);                                        // B15
  asm volatile("s_waitcnt vmcnt(6) lgkmcnt(0)" ::: "memory");  // drain B14
  block_sync();
  MFMAK(0);
  block_sync();
  // tile 15 (CB=1, fa1): entry queue [A15(4), B15(2)] = 6
  asm volatile("s_waitcnt vmcnt(2)" ::: "memory");     // drain A15
  WRITEA1();
  asm volatile("s_waitcnt vmcnt(0) lgkmcnt(0)" ::: "memory");  // drain B15
  block_sync();
  MFMAK(1);
  block_sync();

  // epilogues: LDS transpose (T = lds[0..16384), 32KB) -> u16x8 stores
  if (z == 2) {
    // V: T[c][s] (128x128, swizzled) -> Vt[(b*16+h)*64+d][s]
    u16* T = lds;
#pragma unroll
    for (int m = 0; m < 4; m++)
#pragma unroll
      for (int n = 0; n < 2; n++)
#pragma unroll
        for (int r = 0; r < 4; r++) {
          int sl = wr + m * 16 + lg * 4 + r;
          int cl = wc + n * 16 + lr;
          T[cl * 128 + (sl ^ ((cl & 7) << 3))] = f2bf(acc[m][n][r]);
        }
    __syncthreads();
    const int cl = tid >> 2, s0 = (tid & 3) * 32;
    const int gc = bcol0 + cl;
    const size_t vrow = ((size_t)(arow0 >> 11) * 16 + (gc >> 6)) * 64 + (gc & 63);
    u16* vd = Vt + vrow * 2048 + (size_t)(arow0 & 2047);
#pragma unroll
    for (int j = 0; j < 4; j++) {
      int sl = s0 + j * 8;
      *(u16x8*)&vd[sl] = *(const u16x8*)&T[cl * 128 + (sl ^ ((cl & 7) << 3))];
    }
  } else {
    // Q/K: T[s][c] (128x128, swizzled) -> dst[(bh*2048+s)*64 + c]
    const float scale = (z == 0) ? 0.18033688f : 1.0f;  // 0.125 * log2(e)
    u16* dst = (z == 0) ? Qh : Kh;
    u16* T = lds;
#pragma unroll
    for (int m = 0; m < 4; m++)
#pragma unroll
      for (int n = 0; n < 2; n++)
#pragma unroll
        for (int r = 0; r < 4; r++) {
          int sl = wr + m * 16 + lg * 4 + r;
          int cl = wc + n * 16 + lr;
          T[sl * 128 + (cl ^ ((sl & 7) << 3))] = f2bf(acc[m][n][r] * scale);
        }
    __syncthreads();
    const int h2 = tid >> 8, tt = tid & 255;
    const int rb = tt >> 3, c0 = (tt & 7) * 8;
    const size_t bh = (size_t)(arow0 >> 11) * 16 + bx * 2 + h2;
    const int cl = h2 * 64 + c0;
#pragma unroll
    for (int j = 0; j < 4; j++) {
      int row = j * 32 + rb;
      u16x8 vv = *(const u16x8*)&T[row * 128 + (cl ^ ((row & 7) << 3))];
      *(u16x8*)&dst[(bh * 2048 + (size_t)((arow0 & 2047) + row)) * 64 + c0] = vv;
    }
  }
}

// ---------- kernel 3: flash attention (paired QK^T issue, T15-lite) ----------
// 512 blocks (XCD-swizzled) x 8 waves, 128 q-rows per block, 16 per wave.
__global__ __launch_bounds__(512, 4) void attn_kernel(
    const u16* __restrict__ Qh, const u16* __restrict__ Kh,
    const u16* __restrict__ Vt, u16* __restrict__ Ob) {
  __shared__ u16 kt[4][64 * 64];  // K tiles [key][d], h-swizzled rows
  __shared__ u16 vt[4][64 * 64];  // V^T tiles [d][s], xor-swizzled rows
  const int tid = threadIdx.x;
  const int lane = tid & 63, wave = tid >> 6;
  const int lr = lane & 15, lg = lane >> 4;
  const int id = blockIdx.x;
  const int swz = (id & 7) * 64 + (id >> 3);
  const int bh = swz >> 4;
  const int q0 = (swz & 15) * 128;
  const u16* Qb = Qh + ((size_t)bh * 2048 + q0) * 64;
  const u16* Kb = Kh + (size_t)bh * 2048 * 64;
  const u16* Vb = Vt + (size_t)bh * 64 * 2048;

  bf16x8 aq[2];
#pragma unroll
  for (int kk = 0; kk < 2; kk++)
    aq[kk] = *(const bf16x8*)(Qb + (wave * 16 + lr) * 64 + kk * 32 + lg * 8);

  const int hsw = (lr & 3) | (((lr >> 2) & 1) << 2);
  int koff[2][4];
#pragma unroll
  for (int n = 0; n < 4; n++) {
    int kr = 32 * (n >> 1) + 8 * (lr >> 2) + 4 * (n & 1) + (lr & 3);
#pragma unroll
    for (int kk = 0; kk < 2; kk++)
      koff[kk][n] = kr * 64 + ((kk * 32 + lg * 8) ^ (hsw << 3));
  }
  int voff[2][4];
#pragma unroll
  for (int n = 0; n < 4; n++) {
    int d = n * 16 + lr;
#pragma unroll
    for (int ks = 0; ks < 2; ks++)
      voff[ks][n] = d * 64 + ((ks * 32 + lg * 8) ^ ((d & 7) << 3));
  }

  const int o0 = tid * 8;
  const int srow = tid >> 3, sch = tid & 7;
  const int hk = (srow & 3) | (((srow >> 3) & 1) << 2);
  const u16* kg = Kb + (size_t)srow * 64 + ((sch ^ hk) << 3);
  const u16* vg = Vb + (size_t)srow * 2048 + ((sch ^ (srow & 7)) << 3);

  f32x4 oacc[4] = {};
  float mrun = -1e30f, lrun = 0.f;

  auto STAGE = [&](int t, int b) {
    GLDS16(kg + (size_t)t * 4096, &kt[0][0] + b * 4096 + o0);
    GLDS16(vg + t * 64, &vt[0][0] + b * 4096 + o0);
  };

  auto QKT = [&](int cur, f32x4 (&sacc)[4]) {
    __builtin_amdgcn_s_setprio(1);
#pragma unroll
    for (int kk = 0; kk < 2; kk++) {
#pragma unroll
      for (int n = 0; n < 4; n++) {
        bf16x8 ka = *(const bf16x8*)&kt[cur][koff[kk][n]];
        sacc[n] = __builtin_amdgcn_mfma_f32_16x16x32_bf16(ka, aq[kk],
                                                          sacc[n], 0, 0, 0);
      }
    }
    __builtin_amdgcn_s_setprio(0);
  };

  auto SMPV = [&](int cur, f32x4 (&sacc)[4]) {
    float t0 = fmax3(sacc[0][0], sacc[0][1], sacc[0][2]);
    float t1 = fmax3(sacc[0][3], sacc[1][0], sacc[1][1]);
    float t2 = fmax3(sacc[1][2], sacc[1][3], sacc[2][0]);
    float t3 = fmax3(sacc[2][1], sacc[2][2], sacc[2][3]);
    float t4 = fmax3(sacc[3][0], sacc[3][1], sacc[3][2]);
    float mx = fmaxf(fmax3(t0, t1, t2), fmax3(t3, t4, sacc[3][3]));
    mx = fmaxf(mx, __shfl_xor(mx, 16));
    mx = fmaxf(mx, __shfl_xor(mx, 32));
    float mnew = fmaxf(mrun, mx);
    if (__all(mx - mrun <= 8.0f)) {
      mnew = mrun;
    } else {
      float corr = EXP2(mrun - mnew);
      mrun = mnew;
      lrun *= corr;
      float cr[4];
#pragma unroll
      for (int r = 0; r < 4; r++) cr[r] = __shfl(corr, lg * 4 + r);
#pragma unroll
      for (int n = 0; n < 4; n++)
#pragma unroll
        for (int r = 0; r < 4; r++) oacc[n][r] *= cr[r];
    }
    float psum = 0.f;
#pragma unroll
    for (int n = 0; n < 4; n++)
#pragma unroll
      for (int r = 0; r < 4; r++) {
        float p = EXP2(sacc[n][r] - mnew);
        sacc[n][r] = p;
        psum += p;
      }
    psum += __shfl_xor(psum, 16);
    psum += __shfl_xor(psum, 32);
    lrun += psum;
    u32x4 w0 = {cvt_pk_bf16(sacc[0][0], sacc[0][1]),
                cvt_pk_bf16(sacc[0][2], sacc[0][3]),
                cvt_pk_bf16(sacc[1][0], sacc[1][1]),
                cvt_pk_bf16(sacc[1][2], sacc[1][3])};
    u32x4 w1 = {cvt_pk_bf16(sacc[2][0], sacc[2][1]),
                cvt_pk_bf16(sacc[2][2], sacc[2][3]),
                cvt_pk_bf16(sacc[3][0], sacc[3][1]),
                cvt_pk_bf16(sacc[3][2], sacc[3][3])};
    bf16x8 pa0 = __builtin_bit_cast(bf16x8, w0);
    bf16x8 pa1 = __builtin_bit_cast(bf16x8, w1);
    __builtin_amdgcn_s_setprio(1);
#pragma unroll
    for (int ks = 0; ks < 2; ks++) {
      bf16x8 ap = ks ? pa1 : pa0;
      bf16x8 bv[4];
#pragma unroll
      for (int n = 0; n < 4; n++)
        bv[n] = *(const bf16x8*)&vt[cur][voff[ks][n]];
#pragma unroll
      for (int n = 0; n < 4; n++)
        oacc[n] = __builtin_amdgcn_mfma_f32_16x16x32_bf16(ap, bv[n],
                                                          oacc[n], 0, 0, 0);
    }
    __builtin_amdgcn_s_setprio(0);
  };

  auto COMPUTE2 = [&](int c0, int c1) {  // c0,c1 literals at call sites
    f32x4 s0[4] = {}, s1[4] = {};
    QKT(c0, s0);
    QKT(c1, s1);
    SMPV(c0, s0);
    SMPV(c1, s1);
  };

#define VMC4 asm volatile("s_waitcnt vmcnt(4)" ::: "memory")
#define VMC0 asm volatile("s_waitcnt vmcnt(0)" ::: "memory")
  STAGE(0, 0); STAGE(1, 1);
  // 16 super-steps, 2 tiles each; unrolled x2 so all buf indices are literals
  for (int t = 0; t < 28; t += 4) {   // steps for tiles 0..27
    STAGE(t + 2, 2); STAGE(t + 3, 3); VMC4; block_sync();
    COMPUTE2(0, 1); block_sync();
    STAGE(t + 4, 0); STAGE(t + 5, 1); VMC4; block_sync();
    COMPUTE2(2, 3); block_sync();
  }
  // tiles 28,29 in bufs 0,1 (staged by last iter); stage 30,31
  STAGE(30, 2); STAGE(31, 3); VMC4; block_sync();
  COMPUTE2(0, 1); block_sync();
  VMC0; block_sync();
  COMPUTE2(2, 3);
#undef VMC4
#undef VMC0

  const int b = bh >> 4, h = bh & 15;
  float inv = 1.0f / lrun;
  float ivr[4];
#pragma unroll
  for (int r = 0; r < 4; r++) ivr[r] = __shfl(inv, lg * 4 + r);
#pragma unroll
  for (int r = 0; r < 4; r++) {
    int qrow = q0 + wave * 16 + lg * 4 + r;
#pragma unroll
    for (int n = 0; n < 4; n++) {
      int d = n * 16 + lr;
      Ob[((size_t)b * 2048 + qrow) * 1024 + h * 64 + d] = f2bf(oacc[n][r] * ivr[r]);
    }
  }
}

// ---------- kernel 4: output projection (dbuf + counted vmcnt) ----------
// R22: apply the R19-proven counted-vmcnt 1-deep prefetch (outproj was the
// last kernel still doing a full vmcnt(0) drain per K-step via __syncthreads).
// Double-buffered A (2x16KB) + B (2x8KB) = 48KB LDS; grid 512 = 2/CU (same
// residency as before). Steady step: STAGE(k+1) -> 12 out; vmcnt(6) drains
// tile k; barrier; MFMA(buf k); barrier. Unrolled x2 for literal buf indices.
__global__ __launch_bounds__(256) void outproj_kernel(
    const u16* __restrict__ Ob, const u16* __restrict__ WoT,
    float* __restrict__ out) {
  __shared__ u16 ldsA[2][128 * 64];  // 2x16KB, swizzled rows
  __shared__ u16 ldsB[2][64 * 64];   // 2x8KB, swizzled rows
  const int tid = threadIdx.x;
  const int lane = tid & 63, wave = tid >> 6;
  const int lr = lane & 15, lg = lane >> 4;
  const int wr = (wave >> 1) * 64;  // M offset (0/64)
  const int wc = (wave & 1) * 32;   // N offset (0/32)
  const int id = blockIdx.x;
  const int xcd = id & 7, l = id >> 3;   // l in [0,64)
  const int by = xcd * 4 + (l >> 4);     // 0..31
  const int bx = l & 15;                 // 0..15
  const int arow0 = by * 128, bcol0 = bx * 64;
  f32x4 acc[4][2] = {};

  auto STAGE = [&](int kt, int b) {  // 6 glds: 4 A + 2 B
#pragma unroll
    for (int i = 0; i < 4; i++) {
      int o = (i * 256 + tid) * 8;
      int row = o >> 6, ch = (o >> 3) & 7;
      int sc = (ch ^ (row & 7)) << 3;
      GLDS16(Ob + (size_t)(arow0 + row) * 1024 + kt + sc, &ldsA[b][o]);
    }
#pragma unroll
    for (int i = 0; i < 2; i++) {
      int o = (i * 256 + tid) * 8;
      int row = o >> 6, ch = (o >> 3) & 7;
      int sc = (ch ^ (row & 7)) << 3;
      GLDS16(WoT + (size_t)(bcol0 + row) * 1024 + kt + sc, &ldsB[b][o]);
    }
  };
  auto MFMAK = [&](int b) {
#pragma unroll
    for (int kk = 0; kk < 2; kk++) {
      const int ke = kk * 32 + lg * 8;
      bf16x8 af[4], bfr[2];
#pragma unroll
      for (int m = 0; m < 4; m++) {
        int row = wr + m * 16 + lr;
        af[m] = *(const bf16x8*)&ldsA[b][row * 64 + (ke ^ ((row & 7) << 3))];
      }
#pragma unroll
      for (int n = 0; n < 2; n++) {
        int row = wc + n * 16 + lr;
        bfr[n] = *(const bf16x8*)&ldsB[b][row * 64 + (ke ^ ((row & 7) << 3))];
      }
#pragma unroll
      for (int m = 0; m < 4; m++)
#pragma unroll
        for (int n = 0; n < 2; n++)
          acc[m][n] = __builtin_amdgcn_mfma_f32_16x16x32_bf16(af[m], bfr[n],
                                                              acc[m][n], 0, 0, 0);
    }
  };

#define VMC6 asm volatile("s_waitcnt vmcnt(6)" ::: "memory")
#define VMC0X asm volatile("s_waitcnt vmcnt(0)" ::: "memory")
  STAGE(0, 0);
  for (int kt = 0; kt < 896; kt += 128) {  // tiles 0..13
    STAGE(kt + 64, 1); VMC6; block_sync(); MFMAK(0); block_sync();
    STAGE(kt + 128, 0); VMC6; block_sync(); MFMAK(1); block_sync();
  }
  STAGE(960, 1); VMC6; block_sync(); MFMAK(0); block_sync();  // tile 14
  VMC0X; block_sync(); MFMAK(1);                               // tile 15
#undef VMC6
#undef VMC0X

#pragma unroll
  for (int m = 0; m < 4; m++)
#pragma unroll
    for (int n = 0; n < 2; n++)
#pragma unroll
      for (int r = 0; r < 4; r++) {
        int gr = arow0 + wr + m * 16 + lg * 4 + r;
        int gc = bcol0 + wc + n * 16 + lr;
        out[(size_t)gr * 1024 + gc] = acc[m][n][r];
      }
}

extern "C" void kernel_launch(void* const* d_in, const int* in_sizes, int n_in,
                              void* d_out, int out_size, void* d_ws, size_t ws_size,
                              hipStream_t stream) {
  const float* q  = (const float*)d_in[0];
  const float* k  = (const float*)d_in[1];
  const float* v  = (const float*)d_in[2];
  const float* wq = (const float*)d_in[3];
  const float* wk = (const float*)d_in[4];
  const float* wv = (const float*)d_in[5];
  const float* wo = (const float*)d_in[6];
  float* out = (float*)d_out;
  char* ws = (char*)d_ws;

  u16* WT = (u16*)ws;                                    // [4][1024][1024]
  u16* Qh = (u16*)(ws + (size_t)32 * 1024 * 1024);       // [32][2048][64]
  u16* Kh = (u16*)(ws + (size_t)40 * 1024 * 1024);       // [32][2048][64]
  u16* Vt = (u16*)(ws + (size_t)48 * 1024 * 1024);       // [32][64][2048]
  u16* Ob = (u16*)(ws + (size_t)56 * 1024 * 1024);       // [4096][1024]

  wtrans_kernel<<<dim3(32, 32, 4), 256, 0, stream>>>(wq, wk, wv, wo, WT);
  proj_kernel<<<dim3(768), 512, 0, stream>>>(q, k, v, WT, Qh, Kh, Vt);
  attn_kernel<<<dim3(512), 512, 0, stream>>>(Qh, Kh, Vt, Ob);
  outproj_kernel<<<dim3(512), 256, 0, stream>>>(Ob, WT + (size_t)3 * 1024 * 1024, out);
}

// Round 24
// 112.811 us; speedup vs baseline: 1.0027x; 1.0006x over previous
//
#include <hip/hip_runtime.h>
#include <hip/hip_bf16.h>

// B=2, S=2048, H=16, D=64, D_MODEL=1024, M=B*S=4096
// ws layout (bytes):
//   WT  @ 0MB  : [4][1024][1024] bf16 (w_q^T, w_k^T, w_v^T, w_o^T)  8MB
//   Qh  @ 32MB : [32][2048][64]  bf16 (scaled by 0.125*log2e)       8MB
//   Kh  @ 40MB : [32][2048][64]  bf16                               8MB
//   Vt  @ 48MB : [32][64][2048]  bf16 (per-head transposed V)       8MB
//   Ob  @ 56MB : [4096][1024]    bf16 (attention output)            8MB

using bf16x8 = __attribute__((ext_vector_type(8))) short;
using f32x4  = __attribute__((ext_vector_type(4))) float;
using u32x4  = __attribute__((ext_vector_type(4))) unsigned;
typedef unsigned short u16;
using u16x8 = __attribute__((ext_vector_type(8))) u16;

#define GLDS16(g, l) __builtin_amdgcn_global_load_lds( \
    (const __attribute__((address_space(1))) void*)(g), \
    (__attribute__((address_space(3))) void*)(l), 16, 0, 0)

#if __has_builtin(__builtin_amdgcn_exp2f)
#define EXP2(x) __builtin_amdgcn_exp2f(x)
#else
#define EXP2(x) exp2f(x)
#endif

// Raw s_barrier is IntrNoMem: pair it with compiler memory fences so LDS
// reads/writes cannot be moved across it at compile time.
__device__ __forceinline__ void block_sync() {
  __builtin_amdgcn_sched_barrier(0);
  asm volatile("" ::: "memory");
  __builtin_amdgcn_s_barrier();
  asm volatile("" ::: "memory");
  __builtin_amdgcn_sched_barrier(0);
}

__device__ __forceinline__ u16 f2bf(float f) {
  unsigned u = __builtin_bit_cast(unsigned, f);
  u += 0x7fffu + ((u >> 16) & 1u);
  return (u16)(u >> 16);
}

// packed f32->bf16 RNE (no builtin on gfx950; T12 primitive)
__device__ __forceinline__ unsigned cvt_pk_bf16(float lo, float hi) {
  unsigned r;
  asm("v_cvt_pk_bf16_f32 %0, %1, %2" : "=v"(r) : "v"(lo), "v"(hi));
  return r;
}

__device__ __forceinline__ float fmax3(float a, float b, float c) {
  return fmaxf(fmaxf(a, b), c);  // clang fuses to v_max3_f32
}

// ---------- kernel 1: weight transpose+convert: WT[z][n][k] = bf16(w_z[k][n]) ----------
__global__ __launch_bounds__(256) void wtrans_kernel(
    const float* __restrict__ wq, const float* __restrict__ wk,
    const float* __restrict__ wv, const float* __restrict__ wo,
    u16* __restrict__ dst) {
  __shared__ float t[32][33];
  const int z = blockIdx.z;
  const float* src = (z == 0) ? wq : (z == 1) ? wk : (z == 2) ? wv : wo;
  u16* d = dst + (size_t)z * 1024 * 1024;
  const int tx = threadIdx.x & 31, ty = threadIdx.x >> 5;
  const int bx = blockIdx.x * 32, by = blockIdx.y * 32;
#pragma unroll
  for (int j = 0; j < 4; j++)
    t[ty + j * 8][tx] = src[(size_t)(by + ty + j * 8) * 1024 + bx + tx];
  __syncthreads();
#pragma unroll
  for (int j = 0; j < 4; j++)
    d[(size_t)(bx + ty + j * 8) * 1024 + by + tx] = f2bf(t[tx][ty + j * 8]);
}

// ---------- kernel 2: fused QKV projections (128x128, 512 thr, 2-deep A) ----------
// (R19-validated: VGPR 60, no spill, WRITE 24.6MB exact.)
// In-order vmcnt queue, steady step k: entry [A[k](4),B[k](2),A[k+1](4)]=10;
//   vmcnt(6) drains A[k] -> WRITEA -> issue B[k+1](2)+A[k+2](4) (=12 out) ->
//   vmcnt(10) lgkmcnt(0) drains B[k] -> barrier -> MFMA -> barrier.
// 768 blocks; xcd=id&7 owns 4 y-panels x 8 bx per z -> A read by ONE XCD.
__global__ __launch_bounds__(512, 2) void proj_kernel(
    const float* __restrict__ qf, const float* __restrict__ kf,
    const float* __restrict__ vf, const u16* __restrict__ WT,
    u16* __restrict__ Qh, u16* __restrict__ Kh, u16* __restrict__ Vt) {
  __shared__ u16 lds[24576];   // [0,8192): A; [8192,16384): B0; [16384,24576): B1
  const int id = blockIdx.x;
  const int xcd = id & 7, l = id >> 3;      // l in [0,96)
  const int z = l >> 5, rem = l & 31;       // 32 blocks per XCD per z
  const int by = xcd * 4 + (rem >> 3);      // 4 y-panels per XCD
  const int bx = rem & 7;
  const int arow0 = by * 128, bcol0 = bx * 128;
  const float* A = (z == 0) ? qf : (z == 1) ? kf : vf;
  const u16* Bw = WT + (size_t)z * 1024 * 1024;

  const int tid = threadIdx.x;
  const int lane = tid & 63, wave = tid >> 6;
  const int lr = lane & 15, lg = lane >> 4;
  const int wr = (wave >> 2) * 64;   // M offset (0/64), 2 M-groups
  const int wc = (wave & 3) * 32;    // N offset (0/32/64/96), 4 N-groups
  const int ar = tid >> 2, ac0 = (tid & 3) * 16;  // A stage: row (0..127), col
  f32x4 acc[4][2] = {};
  f32x4 fa0[4], fa1[4];   // 2-deep in-flight A (16 VGPRs each)

  auto LOADA0 = [&](int kt) {
    const float* ap = A + (size_t)(arow0 + ar) * 1024 + kt + ac0;
#pragma unroll
    for (int j = 0; j < 4; j++) fa0[j] = *(const f32x4*)(ap + 4 * j);
  };
  auto LOADA1 = [&](int kt) {
    const float* ap = A + (size_t)(arow0 + ar) * 1024 + kt + ac0;
#pragma unroll
    for (int j = 0; j < 4; j++) fa1[j] = *(const f32x4*)(ap + 4 * j);
  };
  auto GLDSB = [&](int kt, int nb) {
    u16* bd = lds + 8192 + nb * 8192;
#pragma unroll
    for (int i = 0; i < 2; i++) {
      int o = (i * 512 + tid) * 8;
      int row = o >> 6, ch = (o >> 3) & 7;
      GLDS16(Bw + (size_t)(bcol0 + row) * 1024 + kt + ((ch ^ (row & 7)) << 3),
             bd + o);
    }
  };
  auto WRITEA0 = [&]() {
    u32x4 lo = {cvt_pk_bf16(fa0[0][0], fa0[0][1]), cvt_pk_bf16(fa0[0][2], fa0[0][3]),
                cvt_pk_bf16(fa0[1][0], fa0[1][1]), cvt_pk_bf16(fa0[1][2], fa0[1][3])};
    u32x4 hi = {cvt_pk_bf16(fa0[2][0], fa0[2][1]), cvt_pk_bf16(fa0[2][2], fa0[2][3]),
                cvt_pk_bf16(fa0[3][0], fa0[3][1]), cvt_pk_bf16(fa0[3][2], fa0[3][3])};
    const int swz = (ar & 7) << 3;
    *(u32x4*)&lds[ar * 64 + (ac0 ^ swz)] = lo;
    *(u32x4*)&lds[ar * 64 + ((ac0 + 8) ^ swz)] = hi;
  };
  auto WRITEA1 = [&]() {
    u32x4 lo = {cvt_pk_bf16(fa1[0][0], fa1[0][1]), cvt_pk_bf16(fa1[0][2], fa1[0][3]),
                cvt_pk_bf16(fa1[1][0], fa1[1][1]), cvt_pk_bf16(fa1[1][2], fa1[1][3])};
    u32x4 hi = {cvt_pk_bf16(fa1[2][0], fa1[2][1]), cvt_pk_bf16(fa1[2][2], fa1[2][3]),
                cvt_pk_bf16(fa1[3][0], fa1[3][1]), cvt_pk_bf16(fa1[3][2], fa1[3][3])};
    const int swz = (ar & 7) << 3;
    *(u32x4*)&lds[ar * 64 + (ac0 ^ swz)] = lo;
    *(u32x4*)&lds[ar * 64 + ((ac0 + 8) ^ swz)] = hi;
  };
  auto MFMAK = [&](int cb) {
    const u16* Bb = lds + 8192 + cb * 8192;
#pragma unroll
    for (int kk = 0; kk < 2; kk++) {
      bf16x8 af[4], bfr[2];
      const int ke = kk * 32 + lg * 8;
#pragma unroll
      for (int m = 0; m < 4; m++) {
        int row = wr + m * 16 + lr;
        af[m] = *(const bf16x8*)&lds[row * 64 + (ke ^ ((row & 7) << 3))];
      }
#pragma unroll
      for (int n = 0; n < 2; n++) {
        int row = wc + n * 16 + lr;
        bfr[n] = *(const bf16x8*)&Bb[row * 64 + (ke ^ ((row & 7) << 3))];
      }
#pragma unroll
      for (int m = 0; m < 4; m++)
#pragma unroll
        for (int n = 0; n < 2; n++)
          acc[m][n] = __builtin_amdgcn_mfma_f32_16x16x32_bf16(af[m], bfr[n],
                                                              acc[m][n], 0, 0, 0);
    }
  };

  // prologue: queue [A0(4), B0(2), A1(4)] = 10 outstanding
  LOADA0(0);
  GLDSB(0, 0);
  LOADA1(64);
  for (int kt = 0; kt < 896; kt += 128) {   // tiles 0..13 (7 pairs)
    asm volatile("s_waitcnt vmcnt(6)" ::: "memory");   // drain A[k]
    WRITEA0();
    GLDSB(kt + 64, 1);                                  // B[k+1]
    LOADA0(kt + 128);                                   // A[k+2]
    asm volatile("s_waitcnt vmcnt(10) lgkmcnt(0)" ::: "memory");  // drain B[k]
    block_sync();
    MFMAK(0);
    block_sync();
    asm volatile("s_waitcnt vmcnt(6)" ::: "memory");   // drain A[k+1]
    WRITEA1();
    GLDSB(kt + 128, 0);                                 // B[k+2]
    LOADA1(kt + 192);                                   // A[k+3]
    asm volatile("s_waitcnt vmcnt(10) lgkmcnt(0)" ::: "memory");  // drain B[k+1]
    block_sync();
    MFMAK(1);
    block_sync();
  }
  // tile 14 (CB=0, fa0): entry queue [A14(4), B14(2), A15(4)] = 10
  asm volatile("s_waitcnt vmcnt(6)" ::: "memory");     // drain A14
  WRITEA0();
  GLDSB(960, 1);                                        // B15
  asm volatile("s_waitcnt vmcnt(6) lgkmcnt(0)" ::: "memory");  // drain B14
  block_sync();
  MFMAK(0);
  block_sync();
  // tile 15 (CB=1, fa1): entry queue [A15(4), B15(2)] = 6
  asm volatile("s_waitcnt vmcnt(2)" ::: "memory");     // drain A15
  WRITEA1();
  asm volatile("s_waitcnt vmcnt(0) lgkmcnt(0)" ::: "memory");  // drain B15
  block_sync();
  MFMAK(1);
  block_sync();

  // epilogues: LDS transpose (T = lds[0..16384), 32KB) -> u16x8 stores
  if (z == 2) {
    // V: T[c][s] (128x128, swizzled) -> Vt[(b*16+h)*64+d][s]
    u16* T = lds;
#pragma unroll
    for (int m = 0; m < 4; m++)
#pragma unroll
      for (int n = 0; n < 2; n++)
#pragma unroll
        for (int r = 0; r < 4; r++) {
          int sl = wr + m * 16 + lg * 4 + r;
          int cl = wc + n * 16 + lr;
          T[cl * 128 + (sl ^ ((cl & 7) << 3))] = f2bf(acc[m][n][r]);
        }
    __syncthreads();
    const int cl = tid >> 2, s0 = (tid & 3) * 32;
    const int gc = bcol0 + cl;
    const size_t vrow = ((size_t)(arow0 >> 11) * 16 + (gc >> 6)) * 64 + (gc & 63);
    u16* vd = Vt + vrow * 2048 + (size_t)(arow0 & 2047);
#pragma unroll
    for (int j = 0; j < 4; j++) {
      int sl = s0 + j * 8;
      *(u16x8*)&vd[sl] = *(const u16x8*)&T[cl * 128 + (sl ^ ((cl & 7) << 3))];
    }
  } else {
    // Q/K: T[s][c] (128x128, swizzled) -> dst[(bh*2048+s)*64 + c]
    const float scale = (z == 0) ? 0.18033688f : 1.0f;  // 0.125 * log2(e)
    u16* dst = (z == 0) ? Qh : Kh;
    u16* T = lds;
#pragma unroll
    for (int m = 0; m < 4; m++)
#pragma unroll
      for (int n = 0; n < 2; n++)
#pragma unroll
        for (int r = 0; r < 4; r++) {
          int sl = wr + m * 16 + lg * 4 + r;
          int cl = wc + n * 16 + lr;
          T[sl * 128 + (cl ^ ((sl & 7) << 3))] = f2bf(acc[m][n][r] * scale);
        }
    __syncthreads();
    const int h2 = tid >> 8, tt = tid & 255;
    const int rb = tt >> 3, c0 = (tt & 7) * 8;
    const size_t bh = (size_t)(arow0 >> 11) * 16 + bx * 2 + h2;
    const int cl = h2 * 64 + c0;
#pragma unroll
    for (int j = 0; j < 4; j++) {
      int row = j * 32 + rb;
      u16x8 vv = *(const u16x8*)&T[row * 128 + (cl ^ ((row & 7) << 3))];
      *(u16x8*)&dst[(bh * 2048 + (size_t)((arow0 & 2047) + row)) * 64 + c0] = vv;
    }
  }
}

// ---------- kernel 3: flash attention (paired QK^T issue, T15-lite) ----------
// 512 blocks (XCD-swizzled) x 8 waves, 128 q-rows per block, 16 per wave.
__global__ __launch_bounds__(512, 4) void attn_kernel(
    const u16* __restrict__ Qh, const u16* __restrict__ Kh,
    const u16* __restrict__ Vt, u16* __restrict__ Ob) {
  __shared__ u16 kt[4][64 * 64];  // K tiles [key][d], h-swizzled rows
  __shared__ u16 vt[4][64 * 64];  // V^T tiles [d][s], xor-swizzled rows
  const int tid = threadIdx.x;
  const int lane = tid & 63, wave = tid >> 6;
  const int lr = lane & 15, lg = lane >> 4;
  const int id = blockIdx.x;
  const int swz = (id & 7) * 64 + (id >> 3);
  const int bh = swz >> 4;
  const int q0 = (swz & 15) * 128;
  const u16* Qb = Qh + ((size_t)bh * 2048 + q0) * 64;
  const u16* Kb = Kh + (size_t)bh * 2048 * 64;
  const u16* Vb = Vt + (size_t)bh * 64 * 2048;

  bf16x8 aq[2];
#pragma unroll
  for (int kk = 0; kk < 2; kk++)
    aq[kk] = *(const bf16x8*)(Qb + (wave * 16 + lr) * 64 + kk * 32 + lg * 8);

  const int hsw = (lr & 3) | (((lr >> 2) & 1) << 2);
  int koff[2][4];
#pragma unroll
  for (int n = 0; n < 4; n++) {
    int kr = 32 * (n >> 1) + 8 * (lr >> 2) + 4 * (n & 1) + (lr & 3);
#pragma unroll
    for (int kk = 0; kk < 2; kk++)
      koff[kk][n] = kr * 64 + ((kk * 32 + lg * 8) ^ (hsw << 3));
  }
  int voff[2][4];
#pragma unroll
  for (int n = 0; n < 4; n++) {
    int d = n * 16 + lr;
#pragma unroll
    for (int ks = 0; ks < 2; ks++)
      voff[ks][n] = d * 64 + ((ks * 32 + lg * 8) ^ ((d & 7) << 3));
  }

  const int o0 = tid * 8;
  const int srow = tid >> 3, sch = tid & 7;
  const int hk = (srow & 3) | (((srow >> 3) & 1) << 2);
  const u16* kg = Kb + (size_t)srow * 64 + ((sch ^ hk) << 3);
  const u16* vg = Vb + (size_t)srow * 2048 + ((sch ^ (srow & 7)) << 3);

  f32x4 oacc[4] = {};
  float mrun = -1e30f, lrun = 0.f;

  auto STAGE = [&](int t, int b) {
    GLDS16(kg + (size_t)t * 4096, &kt[0][0] + b * 4096 + o0);
    GLDS16(vg + t * 64, &vt[0][0] + b * 4096 + o0);
  };

  auto QKT = [&](int cur, f32x4 (&sacc)[4]) {
    __builtin_amdgcn_s_setprio(1);
#pragma unroll
    for (int kk = 0; kk < 2; kk++) {
#pragma unroll
      for (int n = 0; n < 4; n++) {
        bf16x8 ka = *(const bf16x8*)&kt[cur][koff[kk][n]];
        sacc[n] = __builtin_amdgcn_mfma_f32_16x16x32_bf16(ka, aq[kk],
                                                          sacc[n], 0, 0, 0);
      }
    }
    __builtin_amdgcn_s_setprio(0);
  };

  auto SMPV = [&](int cur, f32x4 (&sacc)[4]) {
    float t0 = fmax3(sacc[0][0], sacc[0][1], sacc[0][2]);
    float t1 = fmax3(sacc[0][3], sacc[1][0], sacc[1][1]);
    float t2 = fmax3(sacc[1][2], sacc[1][3], sacc[2][0]);
    float t3 = fmax3(sacc[2][1], sacc[2][2], sacc[2][3]);
    float t4 = fmax3(sacc[3][0], sacc[3][1], sacc[3][2]);
    float mx = fmaxf(fmax3(t0, t1, t2), fmax3(t3, t4, sacc[3][3]));
    mx = fmaxf(mx, __shfl_xor(mx, 16));
    mx = fmaxf(mx, __shfl_xor(mx, 32));
    float mnew = fmaxf(mrun, mx);
    if (__all(mx - mrun <= 8.0f)) {
      mnew = mrun;
    } else {
      float corr = EXP2(mrun - mnew);
      mrun = mnew;
      lrun *= corr;
      float cr[4];
#pragma unroll
      for (int r = 0; r < 4; r++) cr[r] = __shfl(corr, lg * 4 + r);
#pragma unroll
      for (int n = 0; n < 4; n++)
#pragma unroll
        for (int r = 0; r < 4; r++) oacc[n][r] *= cr[r];
    }
    float psum = 0.f;
#pragma unroll
    for (int n = 0; n < 4; n++)
#pragma unroll
      for (int r = 0; r < 4; r++) {
        float p = EXP2(sacc[n][r] - mnew);
        sacc[n][r] = p;
        psum += p;
      }
    psum += __shfl_xor(psum, 16);
    psum += __shfl_xor(psum, 32);
    lrun += psum;
    u32x4 w0 = {cvt_pk_bf16(sacc[0][0], sacc[0][1]),
                cvt_pk_bf16(sacc[0][2], sacc[0][3]),
                cvt_pk_bf16(sacc[1][0], sacc[1][1]),
                cvt_pk_bf16(sacc[1][2], sacc[1][3])};
    u32x4 w1 = {cvt_pk_bf16(sacc[2][0], sacc[2][1]),
                cvt_pk_bf16(sacc[2][2], sacc[2][3]),
                cvt_pk_bf16(sacc[3][0], sacc[3][1]),
                cvt_pk_bf16(sacc[3][2], sacc[3][3])};
    bf16x8 pa0 = __builtin_bit_cast(bf16x8, w0);
    bf16x8 pa1 = __builtin_bit_cast(bf16x8, w1);
    __builtin_amdgcn_s_setprio(1);
#pragma unroll
    for (int ks = 0; ks < 2; ks++) {
      bf16x8 ap = ks ? pa1 : pa0;
      bf16x8 bv[4];
#pragma unroll
      for (int n = 0; n < 4; n++)
        bv[n] = *(const bf16x8*)&vt[cur][voff[ks][n]];
#pragma unroll
      for (int n = 0; n < 4; n++)
        oacc[n] = __builtin_amdgcn_mfma_f32_16x16x32_bf16(ap, bv[n],
                                                          oacc[n], 0, 0, 0);
    }
    __builtin_amdgcn_s_setprio(0);
  };

  auto COMPUTE2 = [&](int c0, int c1) {  // c0,c1 literals at call sites
    f32x4 s0[4] = {}, s1[4] = {};
    QKT(c0, s0);
    QKT(c1, s1);
    SMPV(c0, s0);
    SMPV(c1, s1);
  };

#define VMC4 asm volatile("s_waitcnt vmcnt(4)" ::: "memory")
#define VMC0 asm volatile("s_waitcnt vmcnt(0)" ::: "memory")
  STAGE(0, 0); STAGE(1, 1);
  // 16 super-steps, 2 tiles each; unrolled x2 so all buf indices are literals
  for (int t = 0; t < 28; t += 4) {   // steps for tiles 0..27
    STAGE(t + 2, 2); STAGE(t + 3, 3); VMC4; block_sync();
    COMPUTE2(0, 1); block_sync();
    STAGE(t + 4, 0); STAGE(t + 5, 1); VMC4; block_sync();
    COMPUTE2(2, 3); block_sync();
  }
  // tiles 28,29 in bufs 0,1 (staged by last iter); stage 30,31
  STAGE(30, 2); STAGE(31, 3); VMC4; block_sync();
  COMPUTE2(0, 1); block_sync();
  VMC0; block_sync();
  COMPUTE2(2, 3);
#undef VMC4
#undef VMC0

  const int b = bh >> 4, h = bh & 15;
  float inv = 1.0f / lrun;
  float ivr[4];
#pragma unroll
  for (int r = 0; r < 4; r++) ivr[r] = __shfl(inv, lg * 4 + r);
#pragma unroll
  for (int r = 0; r < 4; r++) {
    int qrow = q0 + wave * 16 + lg * 4 + r;
#pragma unroll
    for (int n = 0; n < 4; n++) {
      int d = n * 16 + lr;
      Ob[((size_t)b * 2048 + qrow) * 1024 + h * 64 + d] = f2bf(oacc[n][r] * ivr[r]);
    }
  }
}

// ---------- kernel 4: output projection (dbuf + counted vmcnt) ----------
__global__ __launch_bounds__(256) void outproj_kernel(
    const u16* __restrict__ Ob, const u16* __restrict__ WoT,
    float* __restrict__ out) {
  __shared__ u16 ldsA[2][128 * 64];  // 2x16KB, swizzled rows
  __shared__ u16 ldsB[2][64 * 64];   // 2x8KB, swizzled rows
  const int tid = threadIdx.x;
  const int lane = tid & 63, wave = tid >> 6;
  const int lr = lane & 15, lg = lane >> 4;
  const int wr = (wave >> 1) * 64;  // M offset (0/64)
  const int wc = (wave & 1) * 32;   // N offset (0/32)
  const int id = blockIdx.x;
  const int xcd = id & 7, l = id >> 3;   // l in [0,64)
  const int by = xcd * 4 + (l >> 4);     // 0..31
  const int bx = l & 15;                 // 0..15
  const int arow0 = by * 128, bcol0 = bx * 64;
  f32x4 acc[4][2] = {};

  auto STAGE = [&](int kt, int b) {  // 6 glds: 4 A + 2 B
#pragma unroll
    for (int i = 0; i < 4; i++) {
      int o = (i * 256 + tid) * 8;
      int row = o >> 6, ch = (o >> 3) & 7;
      int sc = (ch ^ (row & 7)) << 3;
      GLDS16(Ob + (size_t)(arow0 + row) * 1024 + kt + sc, &ldsA[b][o]);
    }
#pragma unroll
    for (int i = 0; i < 2; i++) {
      int o = (i * 256 + tid) * 8;
      int row = o >> 6, ch = (o >> 3) & 7;
      int sc = (ch ^ (row & 7)) << 3;
      GLDS16(WoT + (size_t)(bcol0 + row) * 1024 + kt + sc, &ldsB[b][o]);
    }
  };
  auto MFMAK = [&](int b) {
#pragma unroll
    for (int kk = 0; kk < 2; kk++) {
      const int ke = kk * 32 + lg * 8;
      bf16x8 af[4], bfr[2];
#pragma unroll
      for (int m = 0; m < 4; m++) {
        int row = wr + m * 16 + lr;
        af[m] = *(const bf16x8*)&ldsA[b][row * 64 + (ke ^ ((row & 7) << 3))];
      }
#pragma unroll
      for (int n = 0; n < 2; n++) {
        int row = wc + n * 16 + lr;
        bfr[n] = *(const bf16x8*)&ldsB[b][row * 64 + (ke ^ ((row & 7) << 3))];
      }
#pragma unroll
      for (int m = 0; m < 4; m++)
#pragma unroll
        for (int n = 0; n < 2; n++)
          acc[m][n] = __builtin_amdgcn_mfma_f32_16x16x32_bf16(af[m], bfr[n],
                                                              acc[m][n], 0, 0, 0);
    }
  };

#define VMC6 asm volatile("s_waitcnt vmcnt(6)" ::: "memory")
#define VMC0X asm volatile("s_waitcnt vmcnt(0)" ::: "memory")
  STAGE(0, 0);
  for (int kt = 0; kt < 896; kt += 128) {  // tiles 0..13
    STAGE(kt + 64, 1); VMC6; block_sync(); MFMAK(0); block_sync();
    STAGE(kt + 128, 0); VMC6; block_sync(); MFMAK(1); block_sync();
  }
  STAGE(960, 1); VMC6; block_sync(); MFMAK(0); block_sync();  // tile 14
  VMC0X; block_sync(); MFMAK(1);                               // tile 15
#undef VMC6
#undef VMC0X

#pragma unroll
  for (int m = 0; m < 4; m++)
#pragma unroll
    for (int n = 0; n < 2; n++)
#pragma unroll
      for (int r = 0; r < 4; r++) {
        int gr = arow0 + wr + m * 16 + lg * 4 + r;
        int gc = bcol0 + wc + n * 16 + lr;
        out[(size_t)gr * 1024 + gc] = acc[m][n][r];
      }
}

extern "C" void kernel_launch(void* const* d_in, const int* in_sizes, int n_in,
                              void* d_out, int out_size, void* d_ws, size_t ws_size,
                              hipStream_t stream) {
  const float* q  = (const float*)d_in[0];
  const float* k  = (const float*)d_in[1];
  const float* v  = (const float*)d_in[2];
  const float* wq = (const float*)d_in[3];
  const float* wk = (const float*)d_in[4];
  const float* wv = (const float*)d_in[5];
  const float* wo = (const float*)d_in[6];
  float* out = (float*)d_out;
  char* ws = (char*)d_ws;

  u16* WT = (u16*)ws;                                    // [4][1024][1024]
  u16* Qh = (u16*)(ws + (size_t)32 * 1024 * 1024);       // [32][2048][64]
  u16* Kh = (u16*)(ws + (size_t)40 * 1024 * 1024);       // [32][2048][64]
  u16* Vt = (u16*)(ws + (size_t)48 * 1024 * 1024);       // [32][64][2048]
  u16* Ob = (u16*)(ws + (size_t)56 * 1024 * 1024);       // [4096][1024]

  wtrans_kernel<<<dim3(32, 32, 4), 256, 0, stream>>>(wq, wk, wv, wo, WT);
  proj_kernel<<<dim3(768), 512, 0, stream>>>(q, k, v, WT, Qh, Kh, Vt);
  attn_kernel<<<dim3(512), 512, 0, stream>>>(Qh, Kh, Vt, Ob);
  outproj_kernel<<<dim3(512), 256, 0, stream>>>(Ob, WT + (size_t)3 * 1024 * 1024, out);
}